// Round 9
// baseline (482.246 us; speedup 1.0000x reference)
//
#include <hip/hip_runtime.h>
#include <math.h>

#define N_NODES 50000
#define F 64
#define OUTF 32
#define NX4 (N_NODES * 16)          // float4 count of x
#define NPREP (16384 + 2048 + 128 + 32)

#define B1H 64       // histW blocks
#define HR 25000     // nodes per histW pass (100 KB LDS f32)

#define NRANGE 3125  // ranges of 16 dst nodes: 3125*16 = 50000 exactly
#define CB 256       // count/fill blocks

typedef __bf16 v8bf __attribute__((ext_vector_type(8)));
typedef float v4f __attribute__((ext_vector_type(4)));

static __device__ __forceinline__ unsigned short f2bf(float f) {
    union { float f; unsigned u; } v; v.f = f;
    unsigned r = v.u + 0x7FFFu + ((v.u >> 16) & 1u);   // round-to-nearest-even
    return (unsigned short)(r >> 16);
}
static __device__ __forceinline__ float bf2f(unsigned short h) {
    union { unsigned u; float f; } v; v.u = ((unsigned)h) << 16;
    return v.f;
}

// ---------------- pre: cast x->bf16 pairs (float4-vectorized) + weight prep ----------------
__global__ void pre_kernel(const float4* __restrict__ x4, uint2* __restrict__ xb4,
                           const float* __restrict__ Wxz0, const float* __restrict__ Wxz1,
                           const float* __restrict__ Wxh0, const float* __restrict__ Wxh1,
                           const float* __restrict__ Wlin,
                           const float* __restrict__ bxz, const float* __restrict__ bhz,
                           const float* __restrict__ bxh, const float* __restrict__ bhh,
                           const float* __restrict__ blin,
                           unsigned short* __restrict__ Bt, unsigned short* __restrict__ Wlt,
                           float* __restrict__ bzc, float* __restrict__ blc) {
    int i = blockIdx.x * 256 + threadIdx.x;
    if (i < NX4) {
        float4 v = x4[i];
        uint2 o;
        o.x = (unsigned)f2bf(v.x) | ((unsigned)f2bf(v.y) << 16);
        o.y = (unsigned)f2bf(v.z) | ((unsigned)f2bf(v.w) << 16);
        xb4[i] = o;
    } else {
        int idx = i - NX4;
        if (idx < 16384) {
            int k = idx & 127, n = idx >> 7;
            float v;
            if (k < 64) v = (n < 64) ? Wxz0[k * 64 + n] : Wxh0[k * 64 + (n - 64)];
            else        v = (n < 64) ? Wxz1[(k - 64) * 64 + n] : Wxh1[(k - 64) * 64 + (n - 64)];
            Bt[n * 128 + k] = f2bf(v);
        } else if (idx < 16384 + 2048) {
            int j = idx - 16384; int k = j & 63, n = j >> 6;
            Wlt[n * 64 + k] = f2bf(Wlin[k * 32 + n]);
        } else if (idx < 16384 + 2048 + 128) {
            int j = idx - 16384 - 2048;
            bzc[j] = (j < 64) ? (bxz[j] + bhz[j]) : (bxh[j - 64] + bhh[j - 64]);
        } else if (idx < NPREP) {
            int j = idx - 16384 - 2048 - 128;
            blc[j] = blin[j];
        }
    }
}

// ---------------- histW: LDS-privatized weighted degree histogram (by src), partials ----------------
__launch_bounds__(1024)
__global__ void histw_kernel(const int* __restrict__ src, const float* __restrict__ ew,
                             float* __restrict__ partW, int E) {
    __shared__ float sdeg[HR];   // 100 KB
    int b = blockIdx.x, tid = threadIdx.x;
    int epb = (E + B1H - 1) / B1H;
    int lo = b * epb, hi = min(lo + epb, E);
    #pragma unroll
    for (int pass = 0; pass < 2; ++pass) {
        int base = pass * HR;
        for (int i = tid; i < HR; i += 1024) sdeg[i] = 0.f;
        __syncthreads();
        for (int e = lo + tid; e < hi; e += 1024) {
            int s = src[e];
            unsigned ls = (unsigned)(s - base);
            if (ls < HR) atomicAdd(&sdeg[ls], ew[e]);
        }
        __syncthreads();
        for (int i = tid; i < HR; i += 1024)
            partW[(size_t)b * N_NODES + base + i] = sdeg[i];
        __syncthreads();
    }
}

// ---------------- reduceW: sum partials -> dinv ----------------
__global__ void reducew_kernel(const float* __restrict__ partW, float* __restrict__ dinv) {
    int i = blockIdx.x * 256 + threadIdx.x;
    if (i >= N_NODES) return;
    float s = 0.f;
    #pragma unroll
    for (int b = 0; b < B1H; ++b) s += partW[(size_t)b * N_NODES + i];
    dinv[i] = s > 0.f ? rsqrtf(s) : 0.f;
}

// ---------------- count: per-(range, block) dst counts via LDS ----------------
__launch_bounds__(256)
__global__ void count_kernel(const int* __restrict__ dst, unsigned* __restrict__ cntRB, int E) {
    __shared__ unsigned sc[NRANGE];   // 12.5 KB
    int b = blockIdx.x, tid = threadIdx.x;
    for (int i = tid; i < NRANGE; i += 256) sc[i] = 0u;
    __syncthreads();
    int epb = (E + CB - 1) / CB;
    int lo = b * epb, hi = min(lo + epb, E);
    for (int e = lo + tid; e < hi; e += 256)
        atomicAdd(&sc[((unsigned)dst[e]) >> 4], 1u);
    __syncthreads();
    for (int r = tid; r < NRANGE; r += 256)
        cntRB[(size_t)r * CB + b] = sc[r];
}

// ---------------- scan1: per-range exclusive scan over blocks, emit range totals ----------------
__launch_bounds__(256)
__global__ void scan1_kernel(unsigned* __restrict__ cntRB, unsigned* __restrict__ rtot) {
    __shared__ unsigned s[256];
    int r = blockIdx.x, t = threadIdx.x;
    unsigned v = cntRB[(size_t)r * CB + t];
    s[t] = v;
    __syncthreads();
    #pragma unroll
    for (int d = 1; d < 256; d <<= 1) {
        unsigned a = (t >= d) ? s[t - d] : 0u;
        __syncthreads();
        s[t] += a;
        __syncthreads();
    }
    cntRB[(size_t)r * CB + t] = s[t] - v;   // exclusive over blocks
    if (t == 255) rtot[r] = s[255];
}

// ---------------- scan2: exclusive scan of the 3125 range totals -> rbase ----------------
__launch_bounds__(256)
__global__ void scan2_kernel(const unsigned* __restrict__ rtot, unsigned* __restrict__ rbase) {
    __shared__ unsigned ls[256];
    int t = threadIdx.x;
    unsigned loc[13];
    unsigned s = 0;
    #pragma unroll
    for (int j = 0; j < 13; ++j) {
        int idx = t * 13 + j;
        unsigned v = (idx < NRANGE) ? rtot[idx] : 0u;
        loc[j] = s;
        s += v;
    }
    ls[t] = s;
    __syncthreads();
    #pragma unroll
    for (int d = 1; d < 256; d <<= 1) {
        unsigned a = (t >= d) ? ls[t - d] : 0u;
        __syncthreads();
        ls[t] += a;
        __syncthreads();
    }
    unsigned base = ls[t] - s;
    #pragma unroll
    for (int j = 0; j < 13; ++j) {
        int idx = t * 13 + j;
        if (idx < NRANGE) rbase[idx] = base + loc[j];
    }
}

// ---------------- fill: bucket edges by dst-range, LDS cursors ----------------
__launch_bounds__(256)
__global__ void fill_kernel(const int* __restrict__ src, const int* __restrict__ dst,
                            const float* __restrict__ ew, const float* __restrict__ dinv,
                            const unsigned* __restrict__ rbase, const unsigned* __restrict__ cntRB,
                            uint2* __restrict__ bucket, int E) {
    __shared__ unsigned cur[NRANGE];   // 12.5 KB
    int b = blockIdx.x, tid = threadIdx.x;
    for (int r = tid; r < NRANGE; r += 256)
        cur[r] = rbase[r] + cntRB[(size_t)r * CB + b];
    __syncthreads();
    int epb = (E + CB - 1) / CB;
    int lo = b * epb, hi = min(lo + epb, E);
    for (int e = lo + tid; e < hi; e += 256) {
        unsigned s = (unsigned)src[e];
        unsigned d = (unsigned)dst[e];
        float c = -dinv[s] * ew[e] * dinv[d];
        unsigned r = d >> 4;
        unsigned slot = atomicAdd(&cur[r], 1u);
        bucket[slot] = make_uint2(s | ((d & 15u) << 20), __float_as_uint(c));
    }
}

// ---------------- prop: per-range gather + LDS f32 accumulation (no global atomics) ----------------
// block = 1 range = 16 nodes (4 KB LDS acc). 8 half-wave groups x 32 lanes = 64 features.
__launch_bounds__(256)
__global__ void prop2_kernel(const unsigned* __restrict__ rbase, const unsigned* __restrict__ rtot,
                             const uint2* __restrict__ bucket, const unsigned* __restrict__ xb2,
                             unsigned* __restrict__ Pb2) {
    __shared__ float sacc[16 * 64];   // 4 KB
    int r = blockIdx.x, tid = threadIdx.x;
    for (int i = tid; i < 16 * 64; i += 256) sacc[i] = 0.f;
    __syncthreads();
    unsigned beg = rbase[r], cnt = rtot[r];
    unsigned end = beg + cnt;
    int g = tid >> 5, l32 = tid & 31;
    unsigned i = beg + g;
    for (; i + 8 < end; i += 16) {
        uint2 r1 = bucket[i];
        uint2 r2 = bucket[i + 8];
        unsigned s1 = r1.x & 0xFFFFFu, dl1 = r1.x >> 20;
        unsigned s2 = r2.x & 0xFFFFFu, dl2 = r2.x >> 20;
        float c1 = __uint_as_float(r1.y);
        float c2 = __uint_as_float(r2.y);
        unsigned xv1 = xb2[(size_t)s1 * 32 + l32];
        unsigned xv2 = xb2[(size_t)s2 * 32 + l32];
        atomicAdd(&sacc[dl1 * 64 + 2 * l32],     c1 * bf2f((unsigned short)(xv1 & 0xFFFFu)));
        atomicAdd(&sacc[dl1 * 64 + 2 * l32 + 1], c1 * bf2f((unsigned short)(xv1 >> 16)));
        atomicAdd(&sacc[dl2 * 64 + 2 * l32],     c2 * bf2f((unsigned short)(xv2 & 0xFFFFu)));
        atomicAdd(&sacc[dl2 * 64 + 2 * l32 + 1], c2 * bf2f((unsigned short)(xv2 >> 16)));
    }
    for (; i < end; i += 8) {
        uint2 r1 = bucket[i];
        unsigned s1 = r1.x & 0xFFFFFu, dl1 = r1.x >> 20;
        float c1 = __uint_as_float(r1.y);
        unsigned xv1 = xb2[(size_t)s1 * 32 + l32];
        atomicAdd(&sacc[dl1 * 64 + 2 * l32],     c1 * bf2f((unsigned short)(xv1 & 0xFFFFu)));
        atomicAdd(&sacc[dl1 * 64 + 2 * l32 + 1], c1 * bf2f((unsigned short)(xv1 >> 16)));
    }
    __syncthreads();
    int nbase = r * 16;
    for (int j = tid; j < 16 * 32; j += 256) {
        int dl = j >> 5, f2 = j & 31;
        int node = nbase + dl;
        float a = sacc[dl * 64 + f2 * 2];
        float b = sacc[dl * 64 + f2 * 2 + 1];
        Pb2[(size_t)node * 32 + f2] = (unsigned)f2bf(a) | ((unsigned)f2bf(b) << 16);
    }
}

// ---------------- fused dense (MFMA, persistent): gates GEMM + GRU + linear + L2-normalize ----------------
__launch_bounds__(256, 2)
__global__ void dense_kernel(const unsigned short* __restrict__ xb, const unsigned short* __restrict__ Pb,
                             const unsigned short* __restrict__ Bt, const unsigned short* __restrict__ Wlt,
                             const float* __restrict__ bzc, const float* __restrict__ blc,
                             float* __restrict__ out) {
    __shared__ unsigned short Bs[128 * 136];
    __shared__ unsigned short Wls[32 * 80];
    __shared__ unsigned short Hs[4][16 * 80];
    __shared__ float bzs[128], bls[32];

    int tid = threadIdx.x;
    for (int c = tid; c < 4096; c += 256) {
        int n = c >> 5; int k4 = (c & 31) * 4;
        *(uint2*)&Bs[n * 136 + k4] = *(const uint2*)&Bt[n * 128 + k4];
    }
    for (int c = tid; c < 512; c += 256) {
        int n = c >> 4; int k4 = (c & 15) * 4;
        *(uint2*)&Wls[n * 80 + k4] = *(const uint2*)&Wlt[n * 64 + k4];
    }
    if (tid < 128) bzs[tid] = bzc[tid];
    if (tid < 32) bls[tid] = blc[tid];
    __syncthreads();

    int wv = tid >> 6, lane = tid & 63;
    int nl = lane & 15, q = lane >> 4;
    int ngroups = (N_NODES + 63) / 64;

    for (int g = blockIdx.x; g < ngroups; g += gridDim.x) {
        int rowbase = g * 64 + wv * 16;
        int arow = rowbase + nl; if (arow >= N_NODES) arow = N_NODES - 1;

        v4f acc[8];
        #pragma unroll
        for (int i = 0; i < 8; ++i) acc[i] = (v4f)(0.f);

        #pragma unroll
        for (int kk = 0; kk < 4; ++kk) {
            int k0 = kk * 32 + q * 8;
            const unsigned short* ap = (kk < 2) ? (xb + (size_t)arow * 64 + k0)
                                                : (Pb + (size_t)arow * 64 + (k0 - 64));
            v8bf a = *(const v8bf*)ap;
            #pragma unroll
            for (int tn = 0; tn < 8; ++tn) {
                v8bf b = *(const v8bf*)&Bs[(tn * 16 + nl) * 136 + kk * 32 + q * 8];
                acc[tn] = __builtin_amdgcn_mfma_f32_16x16x32_bf16(a, b, acc[tn], 0, 0, 0);
            }
        }

        #pragma unroll
        for (int tn = 0; tn < 4; ++tn) {
            int n = tn * 16 + nl;
            float bz = bzs[n], bh = bzs[64 + n];
            #pragma unroll
            for (int r = 0; r < 4; ++r) {
                float z = acc[tn][r] + bz;
                float h = acc[tn + 4][r] + bh;
                float sg = 1.f / (1.f + __expf(-z));
                float th = 1.f - 2.f / (__expf(2.f * h) + 1.f);
                int m = q * 4 + r;
                Hs[wv][m * 80 + n] = f2bf((1.f - sg) * th);
            }
        }
        // Hs[wv] is wave-private; compiler's lgkmcnt ordering covers write->read

        v4f acc2[2];
        acc2[0] = (v4f)(0.f); acc2[1] = (v4f)(0.f);
        #pragma unroll
        for (int kk = 0; kk < 2; ++kk) {
            v8bf a = *(const v8bf*)&Hs[wv][nl * 80 + kk * 32 + q * 8];
            #pragma unroll
            for (int tn = 0; tn < 2; ++tn) {
                v8bf b = *(const v8bf*)&Wls[(tn * 16 + nl) * 80 + kk * 32 + q * 8];
                acc2[tn] = __builtin_amdgcn_mfma_f32_16x16x32_bf16(a, b, acc2[tn], 0, 0, 0);
            }
        }

        float o0[4], o1[4];
        #pragma unroll
        for (int r = 0; r < 4; ++r) {
            o0[r] = acc2[0][r] + bls[nl];
            o1[r] = acc2[1][r] + bls[16 + nl];
        }
        #pragma unroll
        for (int r = 0; r < 4; ++r) {
            float ss = o0[r] * o0[r] + o1[r] * o1[r];
            ss += __shfl_xor(ss, 1);
            ss += __shfl_xor(ss, 2);
            ss += __shfl_xor(ss, 4);
            ss += __shfl_xor(ss, 8);
            float dn = fmaxf(sqrtf(ss), 1e-12f);
            int node = rowbase + q * 4 + r;
            if (node < N_NODES) {
                out[node * 32 + nl] = o0[r] / dn;
                out[node * 32 + 16 + nl] = o1[r] / dn;
            }
        }
    }
}

extern "C" void kernel_launch(void* const* d_in, const int* in_sizes, int n_in,
                              void* d_out, int out_size, void* d_ws, size_t ws_size,
                              hipStream_t stream) {
    const float* x    = (const float*)d_in[0];
    const int*   ei   = (const int*)d_in[1];
    const float* ew   = (const float*)d_in[2];
    const float* Wxz0 = (const float*)d_in[3];
    const float* Wxz1 = (const float*)d_in[4];
    const float* bxz  = (const float*)d_in[5];
    const float* bhz  = (const float*)d_in[8];
    const float* Wxh0 = (const float*)d_in[15];
    const float* Wxh1 = (const float*)d_in[16];
    const float* bxh  = (const float*)d_in[17];
    const float* bhh  = (const float*)d_in[20];
    const float* Wlin = (const float*)d_in[21];
    const float* blin = (const float*)d_in[22];
    float* out = (float*)d_out;

    int E = in_sizes[2];
    const int* src = ei;
    const int* dst = ei + E;

    // workspace layout (bytes):
    // [0, 200000)              dinv   (f32)
    // [200000, 6600000)        xb     (bf16 N*64)
    // [6600000, 13000000)      Pb     (bf16 N*64, fully written by prop)
    // [13000000, 25800000)     partW  (f32 64 x N)  [histw -> reducew]
    //   overlays (after reducew):
    //   [13000000, 19400000)   bucket (uint2 E)       [fill -> prop]
    //   [19400000, 22600000)   cntRB  (u32 NRANGE*CB) [count -> fill]
    //   [22600000, 22612512)   rtot   (u32 NRANGE)
    //   [22612512, 22625024)   rbase  (u32 NRANGE)
    // [25800000, ...)          Bt | Wlt | bzc | blc
    char* base = (char*)d_ws;
    float*          dinv   = (float*)(base + 0);
    unsigned short* xb     = (unsigned short*)(base + 200000);
    unsigned short* Pb     = (unsigned short*)(base + 6600000);
    float*          partW  = (float*)(base + 13000000);
    uint2*          bucket = (uint2*)(base + 13000000);
    unsigned*       cntRB  = (unsigned*)(base + 19400000);
    unsigned*       rtot   = (unsigned*)(base + 22600000);
    unsigned*       rbase  = (unsigned*)(base + 22612512);
    char* p = base + 25800000;
    unsigned short* Bt     = (unsigned short*)p;      p += 128 * 128 * 2;
    unsigned short* Wlt    = (unsigned short*)p;      p += 32 * 64 * 2;
    float*          bzc    = (float*)p;               p += 128 * 4;
    float*          blc    = (float*)p;

    pre_kernel<<<(NX4 + NPREP + 255) / 256, 256, 0, stream>>>(
        (const float4*)x, (uint2*)xb,
        Wxz0, Wxz1, Wxh0, Wxh1, Wlin, bxz, bhz, bxh, bhh, blin,
        Bt, Wlt, bzc, blc);

    histw_kernel<<<B1H, 1024, 0, stream>>>(src, ew, partW, E);
    reducew_kernel<<<(N_NODES + 255) / 256, 256, 0, stream>>>(partW, dinv);

    count_kernel<<<CB, 256, 0, stream>>>(dst, cntRB, E);
    scan1_kernel<<<NRANGE, 256, 0, stream>>>(cntRB, rtot);
    scan2_kernel<<<1, 256, 0, stream>>>(rtot, rbase);
    fill_kernel<<<CB, 256, 0, stream>>>(src, dst, ew, dinv, rbase, cntRB, bucket, E);
    prop2_kernel<<<NRANGE, 256, 0, stream>>>(rbase, rtot, bucket, (const unsigned*)xb, (unsigned*)Pb);

    dense_kernel<<<512, 256, 0, stream>>>(xb, Pb, Bt, Wlt, bzc, blc, out);
}

// Round 10
// 242.893 us; speedup vs baseline: 1.9854x; 1.9854x over previous
//
#include <hip/hip_runtime.h>
#include <math.h>

#define N_NODES 50000
#define F 64
#define OUTF 32
#define NX4 (N_NODES * 16)          // float4 count of x
#define NPREP (16384 + 2048 + 128 + 32)
#define NPBZ (N_NODES * 8)          // uint4 count of Pb

#define HCHUNK 64    // edge chunks for histW
#define HR 25000     // nodes per half (100 KB LDS f32)

typedef __bf16 v8bf __attribute__((ext_vector_type(8)));
typedef float v4f __attribute__((ext_vector_type(4)));

static __device__ __forceinline__ unsigned short f2bf(float f) {
    union { float f; unsigned u; } v; v.f = f;
    unsigned r = v.u + 0x7FFFu + ((v.u >> 16) & 1u);   // round-to-nearest-even
    return (unsigned short)(r >> 16);
}
static __device__ __forceinline__ float bf2f(unsigned short h) {
    union { unsigned u; float f; } v; v.u = ((unsigned)h) << 16;
    return v.f;
}

// ---------------- pre: cast x->bf16 (float4-vec) + weight prep + zero Pb ----------------
__global__ void pre_kernel(const float4* __restrict__ x4, uint2* __restrict__ xb4,
                           uint4* __restrict__ Pb16,
                           const float* __restrict__ Wxz0, const float* __restrict__ Wxz1,
                           const float* __restrict__ Wxh0, const float* __restrict__ Wxh1,
                           const float* __restrict__ Wlin,
                           const float* __restrict__ bxz, const float* __restrict__ bhz,
                           const float* __restrict__ bxh, const float* __restrict__ bhh,
                           const float* __restrict__ blin,
                           unsigned short* __restrict__ Bt, unsigned short* __restrict__ Wlt,
                           float* __restrict__ bzc, float* __restrict__ blc) {
    int i = blockIdx.x * 256 + threadIdx.x;
    if (i < NX4) {
        float4 v = x4[i];
        uint2 o;
        o.x = (unsigned)f2bf(v.x) | ((unsigned)f2bf(v.y) << 16);
        o.y = (unsigned)f2bf(v.z) | ((unsigned)f2bf(v.w) << 16);
        xb4[i] = o;
    } else if (i < NX4 + NPBZ) {
        Pb16[i - NX4] = make_uint4(0u, 0u, 0u, 0u);
    } else {
        int idx = i - NX4 - NPBZ;
        if (idx < 16384) {
            int k = idx & 127, n = idx >> 7;
            float v;
            if (k < 64) v = (n < 64) ? Wxz0[k * 64 + n] : Wxh0[k * 64 + (n - 64)];
            else        v = (n < 64) ? Wxz1[(k - 64) * 64 + n] : Wxh1[(k - 64) * 64 + (n - 64)];
            Bt[n * 128 + k] = f2bf(v);
        } else if (idx < 16384 + 2048) {
            int j = idx - 16384; int k = j & 63, n = j >> 6;
            Wlt[n * 64 + k] = f2bf(Wlin[k * 32 + n]);
        } else if (idx < 16384 + 2048 + 128) {
            int j = idx - 16384 - 2048;
            bzc[j] = (j < 64) ? (bxz[j] + bhz[j]) : (bxh[j - 64] + bhh[j - 64]);
        } else if (idx < NPREP) {
            int j = idx - 16384 - 2048 - 128;
            blc[j] = blin[j];
        }
    }
}

// ---------------- histW: 128 blocks = 64 edge-chunks x 2 node-halves, 1 pass each ----------------
__launch_bounds__(1024)
__global__ void histw_kernel(const int* __restrict__ src, const float* __restrict__ ew,
                             float* __restrict__ partW, int E) {
    __shared__ float sdeg[HR];   // 100 KB
    int b = blockIdx.x, tid = threadIdx.x;
    int chunk = b >> 1, half = b & 1;
    int nbase = half * HR;
    int epb = (E + HCHUNK - 1) / HCHUNK;
    int lo = chunk * epb, hi = min(lo + epb, E);
    for (int i = tid; i < HR; i += 1024) sdeg[i] = 0.f;
    __syncthreads();
    for (int e = lo + tid; e < hi; e += 1024) {
        int s = src[e];
        unsigned ls = (unsigned)(s - nbase);
        if (ls < HR) atomicAdd(&sdeg[ls], ew[e]);
    }
    __syncthreads();
    for (int i = tid; i < HR; i += 1024)
        partW[(size_t)chunk * N_NODES + nbase + i] = sdeg[i];
}

// ---------------- reduceW: sum partials -> dinv ----------------
__global__ void reducew_kernel(const float* __restrict__ partW, float* __restrict__ dinv) {
    int i = blockIdx.x * 256 + threadIdx.x;
    if (i >= N_NODES) return;
    float s = 0.f;
    #pragma unroll
    for (int b = 0; b < HCHUNK; ++b) s += partW[(size_t)b * N_NODES + i];
    dinv[i] = s > 0.f ? rsqrtf(s) : 0.f;
}

// ---------------- scatter: Pb[d,:] += coef * xb[s,:]  (coalesced packed bf16 atomics) ----------------
// 2 edges per wave; 32 lanes/edge; each lane handles 2 features via pk_add_bf16
__global__ void scatter_kernel(const int* __restrict__ src, const int* __restrict__ dst,
                               const float* __restrict__ w, const float* __restrict__ dinv,
                               const unsigned int* __restrict__ xb2, unsigned int* __restrict__ Pb2,
                               int E) {
    int t = blockIdx.x * 256 + threadIdx.x;
    int e = t >> 5;
    if (e >= E) return;
    int lane = t & 31;
    int s = src[e], d = dst[e];
    if ((unsigned)s >= N_NODES || (unsigned)d >= N_NODES) return;
    float coef = -dinv[s] * w[e] * dinv[d];
    unsigned xv = xb2[(size_t)s * 32 + lane];
    unsigned short lo = f2bf(coef * bf2f((unsigned short)(xv & 0xFFFFu)));
    unsigned short hi = f2bf(coef * bf2f((unsigned short)(xv >> 16)));
    unsigned packed = (unsigned)lo | ((unsigned)hi << 16);
    unsigned int* addr = Pb2 + (size_t)d * 32 + lane;
    asm volatile("global_atomic_pk_add_bf16 %0, %1, off" :: "v"(addr), "v"(packed) : "memory");
}

// ---------------- fused dense (MFMA, persistent): gates GEMM + GRU + linear + L2-normalize ----------------
__launch_bounds__(256, 2)
__global__ void dense_kernel(const unsigned short* __restrict__ xb, const unsigned short* __restrict__ Pb,
                             const unsigned short* __restrict__ Bt, const unsigned short* __restrict__ Wlt,
                             const float* __restrict__ bzc, const float* __restrict__ blc,
                             float* __restrict__ out) {
    __shared__ unsigned short Bs[128 * 136];
    __shared__ unsigned short Wls[32 * 80];
    __shared__ unsigned short Hs[4][16 * 80];
    __shared__ float bzs[128], bls[32];

    int tid = threadIdx.x;
    for (int c = tid; c < 4096; c += 256) {
        int n = c >> 5; int k4 = (c & 31) * 4;
        *(uint2*)&Bs[n * 136 + k4] = *(const uint2*)&Bt[n * 128 + k4];
    }
    for (int c = tid; c < 512; c += 256) {
        int n = c >> 4; int k4 = (c & 15) * 4;
        *(uint2*)&Wls[n * 80 + k4] = *(const uint2*)&Wlt[n * 64 + k4];
    }
    if (tid < 128) bzs[tid] = bzc[tid];
    if (tid < 32) bls[tid] = blc[tid];
    __syncthreads();

    int wv = tid >> 6, lane = tid & 63;
    int nl = lane & 15, q = lane >> 4;
    int ngroups = (N_NODES + 63) / 64;

    for (int g = blockIdx.x; g < ngroups; g += gridDim.x) {
        int rowbase = g * 64 + wv * 16;
        int arow = rowbase + nl; if (arow >= N_NODES) arow = N_NODES - 1;

        v4f acc[8];
        #pragma unroll
        for (int i = 0; i < 8; ++i) acc[i] = (v4f)(0.f);

        #pragma unroll
        for (int kk = 0; kk < 4; ++kk) {
            int k0 = kk * 32 + q * 8;
            const unsigned short* ap = (kk < 2) ? (xb + (size_t)arow * 64 + k0)
                                                : (Pb + (size_t)arow * 64 + (k0 - 64));
            v8bf a = *(const v8bf*)ap;
            #pragma unroll
            for (int tn = 0; tn < 8; ++tn) {
                v8bf b = *(const v8bf*)&Bs[(tn * 16 + nl) * 136 + kk * 32 + q * 8];
                acc[tn] = __builtin_amdgcn_mfma_f32_16x16x32_bf16(a, b, acc[tn], 0, 0, 0);
            }
        }

        #pragma unroll
        for (int tn = 0; tn < 4; ++tn) {
            int n = tn * 16 + nl;
            float bz = bzs[n], bh = bzs[64 + n];
            #pragma unroll
            for (int r = 0; r < 4; ++r) {
                float z = acc[tn][r] + bz;
                float h = acc[tn + 4][r] + bh;
                float sg = 1.f / (1.f + __expf(-z));
                float th = 1.f - 2.f / (__expf(2.f * h) + 1.f);
                int m = q * 4 + r;
                Hs[wv][m * 80 + n] = f2bf((1.f - sg) * th);
            }
        }
        // Hs[wv] is wave-private; compiler's lgkmcnt ordering covers write->read

        v4f acc2[2];
        acc2[0] = (v4f)(0.f); acc2[1] = (v4f)(0.f);
        #pragma unroll
        for (int kk = 0; kk < 2; ++kk) {
            v8bf a = *(const v8bf*)&Hs[wv][nl * 80 + kk * 32 + q * 8];
            #pragma unroll
            for (int tn = 0; tn < 2; ++tn) {
                v8bf b = *(const v8bf*)&Wls[(tn * 16 + nl) * 80 + kk * 32 + q * 8];
                acc2[tn] = __builtin_amdgcn_mfma_f32_16x16x32_bf16(a, b, acc2[tn], 0, 0, 0);
            }
        }

        float o0[4], o1[4];
        #pragma unroll
        for (int r = 0; r < 4; ++r) {
            o0[r] = acc2[0][r] + bls[nl];
            o1[r] = acc2[1][r] + bls[16 + nl];
        }
        #pragma unroll
        for (int r = 0; r < 4; ++r) {
            float ss = o0[r] * o0[r] + o1[r] * o1[r];
            ss += __shfl_xor(ss, 1);
            ss += __shfl_xor(ss, 2);
            ss += __shfl_xor(ss, 4);
            ss += __shfl_xor(ss, 8);
            float dn = fmaxf(sqrtf(ss), 1e-12f);
            int node = rowbase + q * 4 + r;
            if (node < N_NODES) {
                out[node * 32 + nl] = o0[r] / dn;
                out[node * 32 + 16 + nl] = o1[r] / dn;
            }
        }
    }
}

extern "C" void kernel_launch(void* const* d_in, const int* in_sizes, int n_in,
                              void* d_out, int out_size, void* d_ws, size_t ws_size,
                              hipStream_t stream) {
    const float* x    = (const float*)d_in[0];
    const int*   ei   = (const int*)d_in[1];
    const float* ew   = (const float*)d_in[2];
    const float* Wxz0 = (const float*)d_in[3];
    const float* Wxz1 = (const float*)d_in[4];
    const float* bxz  = (const float*)d_in[5];
    const float* bhz  = (const float*)d_in[8];
    const float* Wxh0 = (const float*)d_in[15];
    const float* Wxh1 = (const float*)d_in[16];
    const float* bxh  = (const float*)d_in[17];
    const float* bhh  = (const float*)d_in[20];
    const float* Wlin = (const float*)d_in[21];
    const float* blin = (const float*)d_in[22];
    float* out = (float*)d_out;

    int E = in_sizes[2];
    const int* src = ei;
    const int* dst = ei + E;

    // workspace layout (bytes), all regions disjoint:
    // [0, 200000)              dinv   (f32)
    // [200000, 6600000)        xb     (bf16 N*64)
    // [6600000, 13000000)      Pb     (bf16 N*64, zeroed in pre_kernel)
    // [13000000, 25800000)     partW  (f32 64 x N)
    // [25800000, ...)          Bt | Wlt | bzc | blc
    char* base = (char*)d_ws;
    float*          dinv   = (float*)(base + 0);
    unsigned short* xb     = (unsigned short*)(base + 200000);
    unsigned short* Pb     = (unsigned short*)(base + 6600000);
    float*          partW  = (float*)(base + 13000000);
    char* p = base + 25800000;
    unsigned short* Bt     = (unsigned short*)p;      p += 128 * 128 * 2;
    unsigned short* Wlt    = (unsigned short*)p;      p += 32 * 64 * 2;
    float*          bzc    = (float*)p;               p += 128 * 4;
    float*          blc    = (float*)p;

    pre_kernel<<<(NX4 + NPBZ + NPREP + 255) / 256, 256, 0, stream>>>(
        (const float4*)x, (uint2*)xb, (uint4*)Pb,
        Wxz0, Wxz1, Wxh0, Wxh1, Wlin, bxz, bhz, bxh, bhh, blin,
        Bt, Wlt, bzc, blc);

    histw_kernel<<<HCHUNK * 2, 1024, 0, stream>>>(src, ew, partW, E);
    reducew_kernel<<<(N_NODES + 255) / 256, 256, 0, stream>>>(partW, dinv);

    scatter_kernel<<<((size_t)E * 32 + 255) / 256, 256, 0, stream>>>(
        src, dst, ew, dinv, (const unsigned int*)xb, (unsigned int*)Pb, E);

    dense_kernel<<<512, 256, 0, stream>>>(xb, Pb, Bt, Wlt, bzc, blc, out);
}